// Round 6
// baseline (417.342 us; speedup 1.0000x reference)
//
#include <hip/hip_runtime.h>
#include <cstdint>
#include <cstddef>

typedef __attribute__((ext_vector_type(8))) short short8;   // 8 bf16 (4 VGPRs)
typedef __attribute__((ext_vector_type(4))) float f32x4;    // MFMA acc

// ---------------------------------------------------------------------------
// JAX-compatible threefry2x32 (20 rounds). Host: key derivation. Device: used
// only where bit-exact reproduction matters (Ku, Ki).
// ---------------------------------------------------------------------------
__host__ __device__ inline void tf2x32(uint32_t k0, uint32_t k1,
                                       uint32_t c0, uint32_t c1,
                                       uint32_t* o0, uint32_t* o1) {
  uint32_t ks0 = k0, ks1 = k1, ks2 = k0 ^ k1 ^ 0x1BD11BDAu;
  uint32_t x0 = c0 + ks0, x1 = c1 + ks1;
#define TFR(r) { x0 += x1; x1 = (x1 << (r)) | (x1 >> (32 - (r))); x1 ^= x0; }
  TFR(13) TFR(15) TFR(26) TFR(6)   x0 += ks1; x1 += ks2 + 1u;
  TFR(17) TFR(29) TFR(16) TFR(24)  x0 += ks2; x1 += ks0 + 2u;
  TFR(13) TFR(15) TFR(26) TFR(6)   x0 += ks0; x1 += ks1 + 3u;
  TFR(17) TFR(29) TFR(16) TFR(24)  x0 += ks1; x1 += ks2 + 4u;
  TFR(13) TFR(15) TFR(26) TFR(6)   x0 += ks2; x1 += ks0 + 5u;
#undef TFR
  *o0 = x0; *o1 = x1;
}

__device__ inline float tf_u01(uint32_t k0, uint32_t k1, uint32_t c0, uint32_t c1) {
  uint32_t a, b; tf2x32(k0, k1, c0, c1, &a, &b);
  uint32_t bits = a ^ b;
  return __uint_as_float((bits >> 9) | 0x3f800000u) - 1.0f;
}

// Cheap hash for own-RNG draws (Vu/Vi) — FROZEN (absmax-64 validated r4/r5).
__device__ inline float mur_u01(uint32_t z, uint32_t salt) {
  z ^= salt;
  z ^= z >> 16; z *= 0x85ebca6bu;
  z ^= z >> 13; z *= 0xc2b2ae35u;
  z ^= z >> 16;
  return __uint_as_float((z >> 9) | 0x3f800000u) - 1.0f;
}

__device__ inline int bsearch_right(const float* cdf, int C, float u) {
  int lo = 0, hi = C;
  while (lo < hi) { int mid = (lo + hi) >> 1; if (cdf[mid] <= u) lo = mid + 1; else hi = mid; }
  return lo < C ? lo : C - 1;
}

// fp32 -> bf16 (round-nearest-even), packed pair
__device__ inline uint32_t bfpack(float x, float y) {
  uint32_t a = __float_as_uint(x), b = __float_as_uint(y);
  a = (a + 0x7fffu + ((a >> 16) & 1u)) >> 16;
  b = (b + 0x7fffu + ((b >> 16) & 1u)) >> 16;
  return a | (b << 16);
}

// ---------------------------------------------------------------------------
__global__ void init_out(float* out) {
  if (threadIdx.x < 5) out[threadIdx.x] = 0.0f;
}

// transpose: in (R x C) -> out (C x R). R=4096, C=2048.
__global__ void transpose_k(const float* __restrict__ in, float* __restrict__ out,
                            int R, int C) {
  __shared__ float tile[32][33];
  int bx = blockIdx.x * 32;
  int by = blockIdx.y * 32;
  int tx = threadIdx.x, ty = threadIdx.y;
#pragma unroll
  for (int q = 0; q < 32; q += 8)
    tile[ty + q][tx] = in[(size_t)(by + ty + q) * C + (bx + tx)];
  __syncthreads();
#pragma unroll
  for (int q = 0; q < 32; q += 8)
    out[(size_t)(bx + ty + q) * R + (by + tx)] = tile[tx][ty + q];
}

// ---------------------------------------------------------------------------
// X = A (M x 64) @ B (N x 64)^T, 64x64 tile per block (fp32 VALU path — only
// ~12 us combined for Xvu/Xvi; x feeds hinge terms, keep fp32).
// ---------------------------------------------------------------------------
__global__ __launch_bounds__(256) void gemm_nt(
    const float* __restrict__ Arows, const float* __restrict__ Brows,
    float* __restrict__ X, int N) {
  __shared__ __align__(16) float At[64 * 68];
  __shared__ __align__(16) float Bt[64 * 68];
  const int t = threadIdx.x;
  const int i0 = blockIdx.x * 64, j0 = blockIdx.y * 64;
  for (int idx = t; idx < 1024; idx += 256) {
    int row = idx >> 4, q = idx & 15;
    float4 va = *(const float4*)(Arows + (size_t)(i0 + row) * 64 + 4 * q);
    At[(4 * q + 0) * 68 + row] = va.x; At[(4 * q + 1) * 68 + row] = va.y;
    At[(4 * q + 2) * 68 + row] = va.z; At[(4 * q + 3) * 68 + row] = va.w;
    float4 vb = *(const float4*)(Brows + (size_t)(j0 + row) * 64 + 4 * q);
    Bt[(4 * q + 0) * 68 + row] = vb.x; Bt[(4 * q + 1) * 68 + row] = vb.y;
    Bt[(4 * q + 2) * 68 + row] = vb.z; Bt[(4 * q + 3) * 68 + row] = vb.w;
  }
  __syncthreads();
  const int ti = t >> 4, tj = t & 15;
  float acc[4][4] = {{0.f,0.f,0.f,0.f},{0.f,0.f,0.f,0.f},{0.f,0.f,0.f,0.f},{0.f,0.f,0.f,0.f}};
  for (int k = 0; k < 64; ++k) {
    const float4 a = *(const float4*)&At[k * 68 + 4 * ti];
    const float4 b = *(const float4*)&Bt[k * 68 + 4 * tj];
    const float av[4] = {a.x, a.y, a.z, a.w};
    const float bv[4] = {b.x, b.y, b.z, b.w};
#pragma unroll
    for (int p = 0; p < 4; ++p)
#pragma unroll
      for (int q2 = 0; q2 < 4; ++q2) acc[p][q2] += av[p] * bv[q2];
  }
#pragma unroll
  for (int p = 0; p < 4; ++p) {
    float4 w = make_float4(acc[p][0], acc[p][1], acc[p][2], acc[p][3]);
    *(float4*)(X + (size_t)(i0 + 4 * ti + p) * N + j0 + 4 * tj) = w;
  }
}

// ---------------------------------------------------------------------------
// ii via bf16 MFMA: mean |Kitem @ Vitem^T - structure|, 4096x4096, d=64.
// 64x64 tile per block; 4 waves; wave w does rows [16w,16w+16) x all 64 cols
// via 4 col-tiles x 2 K-halves of mfma_f32_16x16x32_bf16.
// LDS holds A/B in fragment-ready k-major order:
//   region R = rowtile*2 + kk (kk = k/32), element (m,k):
//     lane l = ((k%32)/8)<<4 | (m%16),  j = k%8
//     dword offset = R*260 + l*4 + j/2   (260 = 256 + 4 pad dwords)
// Hot reads: lane-contiguous 16B stride -> conflict-free.
// Verified layouts (learn_hip): C/D col=lane&15,row=(lane>>4)*4+reg;
// A/B [m|n = lane&15][k = (lane>>4)*8 + j].
// ---------------------------------------------------------------------------
__global__ __launch_bounds__(256) void ii_mfma(
    const float* __restrict__ Kitem, const float* __restrict__ Vitem,
    const float* __restrict__ structure_, float* __restrict__ out) {
  __shared__ __align__(16) uint32_t Ab[8 * 260];
  __shared__ __align__(16) uint32_t Bb[8 * 260];
  __shared__ float red[256];
  const int t = threadIdx.x;
  const int i0 = blockIdx.x * 64, j0 = blockIdx.y * 64;

  // stage: thread t handles row m = t>>2, 16-col chunk cq = t&3
  {
    const int m = t >> 2, cq = t & 3;
    const int kk = cq >> 1;            // k/32
    const int q0 = (cq & 1) * 2;       // first quad of this 16-k chunk
    const int R = (m >> 4) * 2 + kk;   // region index
    const int m15 = m & 15;
    const float4* sa = (const float4*)(Kitem + (size_t)(i0 + m) * 64 + cq * 16);
    const float4* sb = (const float4*)(Vitem + (size_t)(j0 + m) * 64 + cq * 16);
    float4 a0 = sa[0], a1 = sa[1], a2 = sa[2], a3 = sa[3];
    float4 b0 = sb[0], b1 = sb[1], b2 = sb[2], b3 = sb[3];
    uint4 ca0 = make_uint4(bfpack(a0.x, a0.y), bfpack(a0.z, a0.w),
                           bfpack(a1.x, a1.y), bfpack(a1.z, a1.w));
    uint4 ca1 = make_uint4(bfpack(a2.x, a2.y), bfpack(a2.z, a2.w),
                           bfpack(a3.x, a3.y), bfpack(a3.z, a3.w));
    uint4 cb0 = make_uint4(bfpack(b0.x, b0.y), bfpack(b0.z, b0.w),
                           bfpack(b1.x, b1.y), bfpack(b1.z, b1.w));
    uint4 cb1 = make_uint4(bfpack(b2.x, b2.y), bfpack(b2.z, b2.w),
                           bfpack(b3.x, b3.y), bfpack(b3.z, b3.w));
    const int o0 = R * 260 + (((q0 + 0) << 4) | m15) * 4;
    const int o1 = R * 260 + (((q0 + 1) << 4) | m15) * 4;
    *(uint4*)(Ab + o0) = ca0;  *(uint4*)(Ab + o1) = ca1;
    *(uint4*)(Bb + o0) = cb0;  *(uint4*)(Bb + o1) = cb1;
  }
  __syncthreads();

  // compute: wave w -> row-tile w
  const int w = t >> 6, l = t & 63;
  short8 afr0 = *(const short8*)(Ab + (w * 2 + 0) * 260 + l * 4);
  short8 afr1 = *(const short8*)(Ab + (w * 2 + 1) * 260 + l * 4);
  f32x4 acc[4];
#pragma unroll
  for (int ct = 0; ct < 4; ++ct) {
    short8 bfr0 = *(const short8*)(Bb + (ct * 2 + 0) * 260 + l * 4);
    short8 bfr1 = *(const short8*)(Bb + (ct * 2 + 1) * 260 + l * 4);
    f32x4 a = {0.0f, 0.0f, 0.0f, 0.0f};
    a = __builtin_amdgcn_mfma_f32_16x16x32_bf16(afr0, bfr0, a, 0, 0, 0);
    a = __builtin_amdgcn_mfma_f32_16x16x32_bf16(afr1, bfr1, a, 0, 0, 0);
    acc[ct] = a;
  }

  // epilogue: |D - structure| ; C/D: col = l&15, row = (l>>4)*4 + reg
  const int col = l & 15, rquad = l >> 4;
  float s = 0.0f;
#pragma unroll
  for (int ct = 0; ct < 4; ++ct) {
    const int gc = j0 + ct * 16 + col;
#pragma unroll
    for (int reg = 0; reg < 4; ++reg) {
      const int gr = i0 + w * 16 + rquad * 4 + reg;
      s += fabsf(acc[ct][reg] - structure_[(size_t)gr * 4096 + gc]);
    }
  }
  red[t] = s; __syncthreads();
  for (int off = 128; off > 0; off >>= 1) {
    if (t < off) red[t] += red[t + off];
    __syncthreads();
  }
  if (t == 0) atomicAdd(out + 4, red[0] * (1.0f / 16777216.0f));
}

// ---------------------------------------------------------------------------
// Contrast kernel v2 (Vu / Vi) — FROZEN (absmax-64 validated r4/r5).
// ---------------------------------------------------------------------------
template <int C, int MODE, bool PRE>
__global__ __launch_bounds__(256) void contrast2(
    const float* __restrict__ padj_mat, size_t rs, size_t cs,
    const float* __restrict__ xmat,
    const float* __restrict__ A, const float* __restrict__ B,
    float* __restrict__ out, int out_idx, uint32_t salt) {
  constexpr int E = C / 256;
  constexpr int LOG2E = (E == 16) ? 4 : 3;
  constexpr int S = (E == 16) ? 260 : 264;
  constexpr int TSZ = (E - 1) * S + 256;
  constexpr int DEPTH = (C == 4096) ? 13 : 12;
  constexpr int NB = 512;
  __shared__ float T[TSZ];
  __shared__ int bs[NB + 1];
  __shared__ float x[PRE ? 1 : C];
  __shared__ __align__(16) float qa[PRE ? 4 : 64];
  __shared__ float red[256];
  __shared__ float wsumsh[4];
  __shared__ int s_pcnt, s_ncnt;
  const int t = threadIdx.x;
  const int r = blockIdx.x;
  const int lane = t & 63, wid = t >> 6;
  const float* xrow = PRE ? (xmat + (size_t)r * C) : nullptr;
  if (t == 0) { s_pcnt = 0; s_ncnt = 0; }
  if (!PRE && t < 64) qa[t] = A[(size_t)r * 64 + t];

  int lp = 0, ln = 0;
  for (int c = t; c < C; c += 256) {
    float v = padj_mat[(size_t)r * rs + (size_t)c * cs];
    T[(c & (E - 1)) * S + (c >> LOG2E)] = v;
    lp += (v > 0.0f) ? 1 : 0;
    if (MODE == 0) ln += (v <= 0.0f && c != r) ? 1 : 0;
    else           ln += ((1.0f - v) > 0.0f) ? 1 : 0;
  }
  if (lp) atomicAdd(&s_pcnt, lp);
  if (ln) atomicAdd(&s_ncnt, ln);
  __syncthreads();

  if (!PRE) {
    const int g = t >> 2, q = t & 3;
    const float4* qa4 = (const float4*)qa;
    for (int c = g; c < C; c += 64) {
      const float4* b4 = (const float4*)(B + (size_t)c * 64);
      float acc = 0.0f;
#pragma unroll
      for (int m = 0; m < 4; ++m) {
        float4 f = b4[q + 4 * m];
        float4 a = qa4[q + 4 * m];
        acc += f.x * a.x + f.y * a.y + f.z * a.z + f.w * a.w;
      }
      acc += __shfl_xor(acc, 1);
      acc += __shfl_xor(acc, 2);
      if (q == 0) x[c] = acc;
    }
    __syncthreads();
  }

  const int pcnt = s_pcnt, ncnt = s_ncnt;
  const int num = min(pcnt, ncnt);
  if (num == 0) return;
  const bool brA = (pcnt <= ncnt);

  auto wf = [&](float v, int c) -> float {
    if (brA) {
      if (MODE == 0) return (v <= 0.0f && c != r) ? 1.0f : 0.0f;
      float nv = 1.0f - v; return nv > 0.0f ? nv : 0.0f;
    }
    return v > 0.0f ? v : 0.0f;
  };

  float csum = 0.0f;
#pragma unroll
  for (int e = 0; e < E; ++e) csum += wf(T[e * S + t], t * E + e);
  float ps = csum;
#pragma unroll
  for (int off = 1; off < 64; off <<= 1) {
    float o = __shfl_up(ps, off);
    if (lane >= off) ps += o;
  }
  if (lane == 63) wsumsh[wid] = ps;
  __syncthreads();
  float wbase = 0.0f;
  for (int w = 0; w < wid; ++w) wbase += wsumsh[w];
  float run = wbase + ps - csum;
  {
#pragma unroll
    for (int e = 0; e < E; ++e) {
      float w = wf(T[e * S + t], t * E + e);
      run += w;
      T[e * S + t] = run;
    }
  }
  __syncthreads();
  const float total = T[(E - 1) * S + 255];

  for (int i = t; i < NB; i += 256) {
    float ub = ((float)i / (float)NB) * total;
    int lo = 0, hi = C;
    for (int it = 0; it < DEPTH; ++it) {
      if (lo < hi) {
        int mid = (lo + hi) >> 1;
        float cv = T[(mid & (E - 1)) * S + (mid >> LOG2E)];
        if (cv <= ub) lo = mid + 1; else hi = mid;
      }
    }
    bs[i] = lo;
  }
  if (t == 0) bs[NB] = C;
  __syncthreads();

  float acc = 0.0f;
  for (int k = 0; k < E; k += 8) {
    int cj[8]; bool dj[8]; float uj[8]; int lo[8], hi[8]; float xc[8];
#pragma unroll
    for (int j = 0; j < 8; ++j) {
      int c = t + (k + j) * 256;
      cj[j] = c;
      float v = padj_mat[(size_t)r * rs + (size_t)c * cs];
      bool det = brA ? (v > 0.0f)
                     : (MODE == 0 ? (v <= 0.0f && c != r) : ((1.0f - v) > 0.0f));
      dj[j] = det;
      xc[j] = PRE ? xrow[c] : x[c];
      float f = mur_u01((uint32_t)(r * C + c), salt);
      uj[j] = f * total;
      int b = (int)(f * (float)NB);
      b = b < NB - 1 ? b : NB - 1; b = b > 0 ? b : 0;
      lo[j] = bs[b]; hi[j] = bs[b + 1];
    }
    for (int it = 0; it < 7; ++it) {
#pragma unroll
      for (int j = 0; j < 8; ++j) {
        int mid = (lo[j] + hi[j]) >> 1;
        float cv = T[(mid & (E - 1)) * S + (mid >> LOG2E)];
        if (lo[j] < hi[j]) {
          if (cv <= uj[j]) lo[j] = mid + 1; else hi[j] = mid;
        }
      }
    }
#pragma unroll
    for (int j = 0; j < 8; ++j) {
      if (dj[j]) {
        int s = lo[j] < C ? lo[j] : C - 1;
        float xs = PRE ? xrow[s] : x[s];
        float term = brA ? (xs - xc[j] + 1.0f) : (xc[j] - xs + 1.0f);
        acc += fmaxf(term, 0.0f);
      }
    }
  }
  red[t] = acc; __syncthreads();
  for (int off = 128; off > 0; off >>= 1) {
    if (t < off) red[t] += red[t + off];
    __syncthreads();
  }
  if (t == 0) atomicAdd(out + out_idx, red[0] / (float)num);
}

// ---------------------------------------------------------------------------
// Ku: EXACT reproduction — FROZEN (passed 5x).
// ---------------------------------------------------------------------------
__global__ __launch_bounds__(256) void ku_kernel(
    const float* __restrict__ KUU, const float* __restrict__ Kuser,
    float* __restrict__ out,
    uint32_t kp0, uint32_t kp1, uint32_t kn0, uint32_t kn1) {
  const int C = 2048;
  constexpr int E = 8, LOG2E = 3, S = 264;
  constexpr int TSZ = (E - 1) * S + 256;
  __shared__ float T[TSZ];
  __shared__ float red[256];
  __shared__ int s_pcnt;
  const int t = threadIdx.x, r = blockIdx.x;
  const float* row = KUU + (size_t)r * 2051;
  if (t == 0) s_pcnt = 0;
  __syncthreads();
  int lp = 0;
  for (int c = t; c < C; c += 256) {
    float v = row[c];
    T[(c & (E - 1)) * S + (c >> LOG2E)] = v > 0.0f ? v : 0.0f;
    lp += (v > 0.0f) ? 1 : 0;
  }
  if (lp) atomicAdd(&s_pcnt, lp);
  __syncthreads();
  const int pcnt = s_pcnt;
  const float n0 = row[2048], n1 = row[2049], n2 = row[2050];
  const int ng0 = (n0 <= 0.0f), ng1 = (n1 <= 0.0f), ng2 = (n2 <= 0.0f);
  const int ncnt = ng0 + ng1 + ng2;
  const int num = min(pcnt, ncnt);
  if (num == 0) return;

  float csum = 0.0f;
#pragma unroll
  for (int e = 0; e < E; ++e) csum += T[e * S + t];
  red[t] = csum; __syncthreads();
  if (t == 0) {
    float run = 0.0f;
    for (int i = 0; i < 256; ++i) { float v = red[i]; red[i] = run; run += v; }
  }
  __syncthreads();
  {
    float run = red[t];
#pragma unroll
    for (int e = 0; e < E; ++e) { run += T[e * S + t]; T[e * S + t] = run; }
  }
  __syncthreads();
  const float total = T[(E - 1) * S + 255];

  if (pcnt > ncnt) {
    float term = 0.0f;
    if (t < num) {
      int ng[3] = {ng0, ng1, ng2};
      int det = -1, cnt = 0;
      for (int q = 0; q < 3; ++q) {
        if (ng[q]) { if (cnt == t) { det = q; break; } cnt++; }
      }
      float f = tf_u01(kp0, kp1, 0u, (uint32_t)(r * 3 + t));
      float u = f * total;
      int lo = 0, hi = C;
      while (lo < hi) {
        int mid = (lo + hi) >> 1;
        float cv = T[(mid & (E - 1)) * S + (mid >> LOG2E)];
        if (cv <= u) lo = mid + 1; else hi = mid;
      }
      int s = lo < C ? lo : C - 1;
      const float* qr = Kuser + (size_t)r * 64;
      const float* qs = Kuser + (size_t)s * 64;
      const float* qn = Kuser + (size_t)(2048 + det) * 64;
      float px = 0.0f, nx = 0.0f;
      for (int k = 0; k < 64; ++k) { float av = qr[k]; px += av * qs[k]; nx += av * qn[k]; }
      term = fmaxf(nx - px + 1.0f, 0.0f);
    }
    red[t] = term; __syncthreads();
    for (int off = 128; off > 0; off >>= 1) {
      if (t < off) red[t] += red[t + off];
      __syncthreads();
    }
    if (t == 0) atomicAdd(out + 1, red[0] / (float)num);
  } else {
    if (t == 0) {
      float pv[3]; int pi[3]; int np = 0;
      for (int c = 0; c < C; ++c) {
        float v = row[c];
        if (v > 0.0f) { if (np < 3) { pv[np] = v; pi[np] = c; } np++; }
      }
      for (int a2 = 1; a2 < np; ++a2) {
        float v = pv[a2]; int id = pi[a2]; int b2 = a2 - 1;
        while (b2 >= 0 && pv[b2] > v) { pv[b2 + 1] = pv[b2]; pi[b2 + 1] = pi[b2]; b2--; }
        pv[b2 + 1] = v; pi[b2 + 1] = id;
      }
      int ng[3] = {ng0, ng1, ng2};
      float ncdf[3]; float runn = 0.0f;
      for (int q = 0; q < 3; ++q) { runn += ng[q] ? 1.0f : 0.0f; ncdf[q] = runn; }
      float ss = 0.0f;
      for (int j = 0; j < num; ++j) {
        float f = tf_u01(kn0, kn1, 0u, (uint32_t)(r * 3 + j));
        float u = f * runn;
        int s = 0; while (s < 3 && ncdf[s] <= u) s++; if (s > 2) s = 2;
        int det = pi[np - num + j];
        const float* qr = Kuser + (size_t)r * 64;
        const float* qd = Kuser + (size_t)det * 64;
        const float* qn = Kuser + (size_t)(2048 + s) * 64;
        float px = 0.0f, nx = 0.0f;
        for (int k = 0; k < 64; ++k) { float av = qr[k]; px += av * qd[k]; nx += av * qn[k]; }
        ss += fmaxf(nx - px + 1.0f, 0.0f);
      }
      atomicAdd(out + 1, ss / (float)num);
    }
  }
}

// ---------------------------------------------------------------------------
// Ki pipeline — FROZEN from round 5 (bit-identical; partitioned rank).
// ---------------------------------------------------------------------------
__global__ __launch_bounds__(256) void ki_prep(
    const float* __restrict__ preference,
    float* __restrict__ cdf_ws, float* __restrict__ vals_ws,
    int* __restrict__ rank_ws, float* __restrict__ meta) {
  const int C = 4096;
  __shared__ float cdf[4096];
  __shared__ float red[256];
  __shared__ int s_pcnt;
  const int t = threadIdx.x, r = blockIdx.x;
  if (t == 0) s_pcnt = 0;
  __syncthreads();
  for (int i = r * 256 + t; i < 5 * C; i += 5 * 256) rank_ws[i] = 0;
  int lp = 0;
  for (int c = t; c < C; c += 256) {
    float v = preference[(size_t)c * 5 + r];
    lp += (v > 0.0f) ? 1 : 0;
    cdf[c] = 1.0f - v;
    vals_ws[(size_t)r * C + c] = v;
  }
  if (lp) atomicAdd(&s_pcnt, lp);
  __syncthreads();
  const int num = s_pcnt;
  const int E = C >> 8;
  const int base = t * E;
  float csum = 0.0f;
  for (int e = 0; e < E; ++e) csum += cdf[base + e];
  red[t] = csum; __syncthreads();
  if (t == 0) {
    float run = 0.0f;
    for (int i = 0; i < 256; ++i) { float v = red[i]; red[i] = run; run += v; }
  }
  __syncthreads();
  {
    float run = red[t];
    for (int e = 0; e < E; ++e) { float w = cdf[base + e]; run += w; cdf[base + e] = run; }
  }
  __syncthreads();
  for (int c = t; c < C; c += 256) cdf_ws[(size_t)r * C + c] = cdf[c];
  if (t == 0) { meta[2 * r] = (float)num; meta[2 * r + 1] = cdf[C - 1]; }
}

__global__ __launch_bounds__(256) void ki_rank_p(
    const float* __restrict__ vals_ws, int* __restrict__ rank_ws) {
  const int C = 4096;
  __shared__ __align__(16) float sv[256];
  const int t = threadIdx.x;
  const int r = blockIdx.y;
  const int z = blockIdx.z;
  const int c0 = blockIdx.x * 256 + t;
  const float* vrow = vals_ws + (size_t)r * C;
  sv[t] = vrow[z * 256 + t];
  __syncthreads();
  const float v0 = vrow[c0];
  const int cbase = z * 256;
  int rank = 0;
  const float4* sv4 = (const float4*)sv;
#pragma unroll 8
  for (int q = 0; q < 64; ++q) {
    float4 w = sv4[q];
    int cb = cbase + 4 * q;
    rank += (w.x < v0 || (w.x == v0 && cb + 0 < c0)) ? 1 : 0;
    rank += (w.y < v0 || (w.y == v0 && cb + 1 < c0)) ? 1 : 0;
    rank += (w.z < v0 || (w.z == v0 && cb + 2 < c0)) ? 1 : 0;
    rank += (w.w < v0 || (w.w == v0 && cb + 3 < c0)) ? 1 : 0;
  }
  if (rank) atomicAdd(&rank_ws[(size_t)r * C + c0], rank);
}

__global__ __launch_bounds__(256) void ki_scatter(
    const int* __restrict__ rank_ws, int* __restrict__ sorted_ws) {
  const int C = 4096;
  const int t = threadIdx.x;
  const int r = blockIdx.y;
  const int c0 = blockIdx.x * 256 + t;
  sorted_ws[(size_t)r * C + rank_ws[(size_t)r * C + c0]] = c0;
}

__global__ __launch_bounds__(256) void ki_draw(
    const float* __restrict__ cdf_ws, const int* __restrict__ sorted_ws,
    const float* __restrict__ meta,
    const float* __restrict__ Kuser, const float* __restrict__ Kitem,
    float* __restrict__ out, uint32_t kn0, uint32_t kn1) {
  const int C = 4096;
  __shared__ float cdf[4096];
  __shared__ __align__(16) float qa[64];
  __shared__ float red[256];
  const int t = threadIdx.x;
  const int r = blockIdx.y;
  const int j = blockIdx.x * 256 + t;
  if (t < 64) qa[t] = Kuser[(size_t)r * 64 + t];
  for (int c = t; c < C; c += 256) cdf[c] = cdf_ws[(size_t)r * C + c];
  __syncthreads();
  const int num = (int)meta[2 * r];
  const float total = meta[2 * r + 1];
  float acc = 0.0f;
  if (j < num) {
    float f = tf_u01(kn0, kn1, 0u, (uint32_t)(r * 4096 + j));
    float u = f * total;
    int s = bsearch_right(cdf, C, u);
    int det = sorted_ws[(size_t)r * C + (C - num + j)];
    const float4* qa4 = (const float4*)qa;
    const float4* bs = (const float4*)(Kitem + (size_t)s * 64);
    const float4* bd = (const float4*)(Kitem + (size_t)det * 64);
    float xs = 0.0f, xd = 0.0f;
#pragma unroll
    for (int m = 0; m < 16; ++m) {
      float4 a4 = qa4[m]; float4 v1 = bs[m]; float4 v2 = bd[m];
      xs += a4.x * v1.x + a4.y * v1.y + a4.z * v1.z + a4.w * v1.w;
      xd += a4.x * v2.x + a4.y * v2.y + a4.z * v2.z + a4.w * v2.w;
    }
    acc = fmaxf(xs - xd + 1.0f, 0.0f) / (float)num;
  }
  red[t] = acc; __syncthreads();
  for (int off = 128; off > 0; off >>= 1) {
    if (t < off) red[t] += red[t + off];
    __syncthreads();
  }
  if (t == 0 && red[0] != 0.0f) atomicAdd(out + 3, red[0]);
}

// Monolithic Ki fallback (tiny-ws path).
__global__ __launch_bounds__(256) void ki_kernel(
    const float* __restrict__ preference, const float* __restrict__ Kuser,
    const float* __restrict__ Kitem, float* __restrict__ out,
    uint32_t kn0, uint32_t kn1) {
  const int C = 4096;
  __shared__ float cdf[4096];
  __shared__ unsigned long long skey[4096];
  __shared__ __align__(16) float qa[64];
  __shared__ float red[256];
  __shared__ int s_pcnt;
  const int t = threadIdx.x, r = blockIdx.x;
  if (t == 0) s_pcnt = 0;
  if (t < 64) qa[t] = Kuser[(size_t)r * 64 + t];
  __syncthreads();
  int lp = 0;
  for (int c = t; c < C; c += 256) {
    float v = preference[(size_t)c * 5 + r];
    lp += (v > 0.0f) ? 1 : 0;
    cdf[c] = 1.0f - v;
    skey[c] = ((unsigned long long)__float_as_uint(v) << 32) | (unsigned)c;
  }
  if (lp) atomicAdd(&s_pcnt, lp);
  __syncthreads();
  const int num = s_pcnt;
  if (num == 0) return;
  const int E = C >> 8;
  const int base = t * E;
  float csum = 0.0f;
  for (int e = 0; e < E; ++e) csum += cdf[base + e];
  red[t] = csum; __syncthreads();
  if (t == 0) {
    float run = 0.0f;
    for (int i = 0; i < 256; ++i) { float v = red[i]; red[i] = run; run += v; }
  }
  __syncthreads();
  {
    float run = red[t];
    for (int e = 0; e < E; ++e) { float w = cdf[base + e]; run += w; cdf[base + e] = run; }
  }
  __syncthreads();
  const float total = cdf[C - 1];
  for (int k = 2; k <= C; k <<= 1) {
    for (int j2 = k >> 1; j2 > 0; j2 >>= 1) {
      for (int i = t; i < C; i += 256) {
        int ixj = i ^ j2;
        if (ixj > i) {
          unsigned long long a = skey[i], b = skey[ixj];
          bool up = ((i & k) == 0);
          if ((a > b) == up) { skey[i] = b; skey[ixj] = a; }
        }
      }
      __syncthreads();
    }
  }
  float acc = 0.0f;
  const float4* qa4 = (const float4*)qa;
  for (int j = t; j < num; j += 256) {
    float f = tf_u01(kn0, kn1, 0u, (uint32_t)(r * 4096 + j));
    float u = f * total;
    int s = bsearch_right(cdf, C, u);
    int det = (int)(skey[C - num + j] & 0xffffffffull);
    const float4* bs = (const float4*)(Kitem + (size_t)s * 64);
    const float4* bd = (const float4*)(Kitem + (size_t)det * 64);
    float xs = 0.0f, xd = 0.0f;
#pragma unroll
    for (int m = 0; m < 16; ++m) {
      float4 a4 = qa4[m]; float4 v1 = bs[m]; float4 v2 = bd[m];
      xs += a4.x * v1.x + a4.y * v1.y + a4.z * v1.z + a4.w * v1.w;
      xd += a4.x * v2.x + a4.y * v2.y + a4.z * v2.z + a4.w * v2.w;
    }
    acc += fmaxf(xs - xd + 1.0f, 0.0f);
  }
  red[t] = acc; __syncthreads();
  for (int off = 128; off > 0; off >>= 1) {
    if (t < off) red[t] += red[t + off];
    __syncthreads();
  }
  if (t == 0) atomicAdd(out + 3, red[0] / (float)num);
}

// ---------------------------------------------------------------------------
extern "C" void kernel_launch(void* const* d_in, const int* in_sizes, int n_in,
                              void* d_out, int out_size, void* d_ws, size_t ws_size,
                              hipStream_t stream) {
  const float* KUU   = (const float*)d_in[0];  // 2051 x 2051
  const float* VUU   = (const float*)d_in[1];  // 2048 x 2048
  const float* Vuser = (const float*)d_in[2];  // 2048 x 64
  const float* Vitem = (const float*)d_in[3];  // 4096 x 64
  const float* Kuser = (const float*)d_in[4];  // 2051 x 64
  const float* Kitem = (const float*)d_in[5];  // 4096 x 64
  const float* pref  = (const float*)d_in[7];  // 4096 x 5
  const float* Vpref = (const float*)d_in[8];  // 4096 x 2048
  const float* structure_ = (const float*)d_in[9];  // 4096 x 4096
  float* out = (float*)d_out;  // 5 floats: (Vu, Ku, Vi, Ki, ii)

  uint32_t k1a, k1b, k3a, k3b;
  tf2x32(0u, 42u, 0u, 1u, &k1a, &k1b);  // k1 (Ku call)
  tf2x32(0u, 42u, 0u, 3u, &k3a, &k3b);  // k3 (Ki call)
  uint32_t kup0, kup1, kun0, kun1, kin0, kin1;
  tf2x32(k1a, k1b, 0u, 0u, &kup0, &kup1);
  tf2x32(k1a, k1b, 0u, 1u, &kun0, &kun1);
  tf2x32(k3a, k3b, 0u, 1u, &kin0, &kin1);

  const uint32_t SALT_VU = 0x8AF1B0C2u;
  const uint32_t SALT_VI = 0x5F356495u;

  // ws layout (full): [VUIt 32MB][Xvi 32MB][Xvu 16MB][ki ~336KB]
  const size_t vuit_bytes = (size_t)2048 * 4096 * sizeof(float);
  const size_t xvi_bytes  = (size_t)2048 * 4096 * sizeof(float);
  const size_t xvu_bytes  = (size_t)2048 * 2048 * sizeof(float);
  const size_t ki_bytes   = (size_t)(4 * 5 * 4096 + 16) * sizeof(float);
  const size_t full_bytes = vuit_bytes + xvi_bytes + xvu_bytes + ki_bytes;

  const bool full = ws_size >= full_bytes;
  const bool mid  = !full && ws_size >= vuit_bytes + ki_bytes;

  hipLaunchKernelGGL(init_out, dim3(1), dim3(64), 0, stream, out);

  if (full) {
    float* VUIt = (float*)d_ws;
    float* Xvi  = (float*)((char*)d_ws + vuit_bytes);
    float* Xvu  = (float*)((char*)d_ws + vuit_bytes + xvi_bytes);
    char*  kib  = (char*)d_ws + vuit_bytes + xvi_bytes + xvu_bytes;
    float* cdf_ws  = (float*)kib;
    float* vals_ws = cdf_ws + 5 * 4096;
    int*   sorted_ws = (int*)(vals_ws + 5 * 4096);
    int*   rank_ws = sorted_ws + 5 * 4096;
    float* meta = (float*)(rank_ws + 5 * 4096);

    hipLaunchKernelGGL(ki_prep, dim3(5), dim3(256), 0, stream,
                       pref, cdf_ws, vals_ws, rank_ws, meta);
    hipLaunchKernelGGL(ki_rank_p, dim3(16, 5, 16), dim3(256), 0, stream,
                       vals_ws, rank_ws);
    hipLaunchKernelGGL(ki_scatter, dim3(16, 5), dim3(256), 0, stream,
                       rank_ws, sorted_ws);
    hipLaunchKernelGGL(ki_draw, dim3(16, 5), dim3(256), 0, stream,
                       cdf_ws, sorted_ws, meta, Kuser, Kitem, out, kin0, kin1);

    hipLaunchKernelGGL(transpose_k, dim3(64, 128), dim3(32, 8), 0, stream,
                       Vpref, VUIt, 4096, 2048);
    hipLaunchKernelGGL(gemm_nt, dim3(32, 32), dim3(256), 0, stream,
                       Vuser, Vuser, Xvu, 2048);
    hipLaunchKernelGGL(gemm_nt, dim3(32, 64), dim3(256), 0, stream,
                       Vuser, Vitem, Xvi, 4096);
    hipLaunchKernelGGL(ii_mfma, dim3(64, 64), dim3(256), 0, stream,
                       Kitem, Vitem, structure_, out);

    hipLaunchKernelGGL((contrast2<2048, 0, true>), dim3(2048), dim3(256), 0, stream,
                       VUU, (size_t)2048, (size_t)1, Xvu, nullptr, nullptr,
                       out, 0, SALT_VU);
    hipLaunchKernelGGL(ku_kernel, dim3(2048), dim3(256), 0, stream,
                       KUU, Kuser, out, kup0, kup1, kun0, kun1);
    hipLaunchKernelGGL((contrast2<4096, 1, true>), dim3(2048), dim3(256), 0, stream,
                       VUIt, (size_t)4096, (size_t)1, Xvi, nullptr, nullptr,
                       out, 2, SALT_VI);
  } else if (mid) {
    float* VUIt = (float*)d_ws;
    char*  kib  = (char*)d_ws + vuit_bytes;
    float* cdf_ws  = (float*)kib;
    float* vals_ws = cdf_ws + 5 * 4096;
    int*   sorted_ws = (int*)(vals_ws + 5 * 4096);
    int*   rank_ws = sorted_ws + 5 * 4096;
    float* meta = (float*)(rank_ws + 5 * 4096);

    hipLaunchKernelGGL(ki_prep, dim3(5), dim3(256), 0, stream,
                       pref, cdf_ws, vals_ws, rank_ws, meta);
    hipLaunchKernelGGL(ki_rank_p, dim3(16, 5, 16), dim3(256), 0, stream,
                       vals_ws, rank_ws);
    hipLaunchKernelGGL(ki_scatter, dim3(16, 5), dim3(256), 0, stream,
                       rank_ws, sorted_ws);
    hipLaunchKernelGGL(ki_draw, dim3(16, 5), dim3(256), 0, stream,
                       cdf_ws, sorted_ws, meta, Kuser, Kitem, out, kin0, kin1);

    hipLaunchKernelGGL(ii_mfma, dim3(64, 64), dim3(256), 0, stream,
                       Kitem, Vitem, structure_, out);
    hipLaunchKernelGGL(transpose_k, dim3(64, 128), dim3(32, 8), 0, stream,
                       Vpref, VUIt, 4096, 2048);
    hipLaunchKernelGGL((contrast2<2048, 0, false>), dim3(2048), dim3(256), 0, stream,
                       VUU, (size_t)2048, (size_t)1, nullptr, Vuser, Vuser,
                       out, 0, SALT_VU);
    hipLaunchKernelGGL(ku_kernel, dim3(2048), dim3(256), 0, stream,
                       KUU, Kuser, out, kup0, kup1, kun0, kun1);
    hipLaunchKernelGGL((contrast2<4096, 1, false>), dim3(2048), dim3(256), 0, stream,
                       VUIt, (size_t)4096, (size_t)1, nullptr, Vuser, Vitem,
                       out, 2, SALT_VI);
  } else {
    hipLaunchKernelGGL(ii_mfma, dim3(64, 64), dim3(256), 0, stream,
                       Kitem, Vitem, structure_, out);
    hipLaunchKernelGGL((contrast2<2048, 0, false>), dim3(2048), dim3(256), 0, stream,
                       VUU, (size_t)2048, (size_t)1, nullptr, Vuser, Vuser,
                       out, 0, SALT_VU);
    hipLaunchKernelGGL(ku_kernel, dim3(2048), dim3(256), 0, stream,
                       KUU, Kuser, out, kup0, kup1, kun0, kun1);
    hipLaunchKernelGGL((contrast2<4096, 1, false>), dim3(2048), dim3(256), 0, stream,
                       Vpref, (size_t)1, (size_t)2048, nullptr, Vuser, Vitem,
                       out, 2, SALT_VI);
    hipLaunchKernelGGL(ki_kernel, dim3(5), dim3(256), 0, stream,
                       pref, Kuser, Kitem, out, kin0, kin1);
  }
}

// Round 7
// 350.025 us; speedup vs baseline: 1.1923x; 1.1923x over previous
//
#include <hip/hip_runtime.h>
#include <cstdint>
#include <cstddef>

typedef __attribute__((ext_vector_type(8))) short short8;   // 8 bf16 (4 VGPRs)
typedef __attribute__((ext_vector_type(4))) float f32x4;    // MFMA acc

// ---------------------------------------------------------------------------
// JAX-compatible threefry2x32 (20 rounds). Host: key derivation. Device: used
// only where bit-exact reproduction matters (Ku, Ki).
// ---------------------------------------------------------------------------
__host__ __device__ inline void tf2x32(uint32_t k0, uint32_t k1,
                                       uint32_t c0, uint32_t c1,
                                       uint32_t* o0, uint32_t* o1) {
  uint32_t ks0 = k0, ks1 = k1, ks2 = k0 ^ k1 ^ 0x1BD11BDAu;
  uint32_t x0 = c0 + ks0, x1 = c1 + ks1;
#define TFR(r) { x0 += x1; x1 = (x1 << (r)) | (x1 >> (32 - (r))); x1 ^= x0; }
  TFR(13) TFR(15) TFR(26) TFR(6)   x0 += ks1; x1 += ks2 + 1u;
  TFR(17) TFR(29) TFR(16) TFR(24)  x0 += ks2; x1 += ks0 + 2u;
  TFR(13) TFR(15) TFR(26) TFR(6)   x0 += ks0; x1 += ks1 + 3u;
  TFR(17) TFR(29) TFR(16) TFR(24)  x0 += ks1; x1 += ks2 + 4u;
  TFR(13) TFR(15) TFR(26) TFR(6)   x0 += ks2; x1 += ks0 + 5u;
#undef TFR
  *o0 = x0; *o1 = x1;
}

__device__ inline float tf_u01(uint32_t k0, uint32_t k1, uint32_t c0, uint32_t c1) {
  uint32_t a, b; tf2x32(k0, k1, c0, c1, &a, &b);
  uint32_t bits = a ^ b;
  return __uint_as_float((bits >> 9) | 0x3f800000u) - 1.0f;
}

// Cheap hash for own-RNG draws (Vu/Vi) — FROZEN (absmax-64 validated r4-r6).
__device__ inline float mur_u01(uint32_t z, uint32_t salt) {
  z ^= salt;
  z ^= z >> 16; z *= 0x85ebca6bu;
  z ^= z >> 13; z *= 0xc2b2ae35u;
  z ^= z >> 16;
  return __uint_as_float((z >> 9) | 0x3f800000u) - 1.0f;
}

__device__ inline int bsearch_right(const float* cdf, int C, float u) {
  int lo = 0, hi = C;
  while (lo < hi) { int mid = (lo + hi) >> 1; if (cdf[mid] <= u) lo = mid + 1; else hi = mid; }
  return lo < C ? lo : C - 1;
}

// fp32 -> bf16 (round-nearest-even), packed pair
__device__ inline uint32_t bfpack(float x, float y) {
  uint32_t a = __float_as_uint(x), b = __float_as_uint(y);
  a = (a + 0x7fffu + ((a >> 16) & 1u)) >> 16;
  b = (b + 0x7fffu + ((b >> 16) & 1u)) >> 16;
  return a | (b << 16);
}

// part-region layout (floats, in ws): Vu[2048] Ku[2048] Vi[2048] Ki[80] ii[4096]
#define PART_VU 0
#define PART_KU 2048
#define PART_VI 4096
#define PART_KI 6144
#define PART_II 6224
#define PART_LEN 10320

// ---------------------------------------------------------------------------
__global__ void init_out(float* out) {
  if (threadIdx.x < 5) out[threadIdx.x] = 0.0f;
}

__global__ void zero_part(float* part) {
  for (int i = blockIdx.x * 256 + threadIdx.x; i < PART_LEN; i += gridDim.x * 256)
    part[i] = 0.0f;
}

// Deterministic final sums: out[idx] = scale * sum(part region idx).
__global__ __launch_bounds__(256) void final_reduce(
    const float* __restrict__ part, float* __restrict__ out) {
  __shared__ float red[256];
  const int t = threadIdx.x;
  const int idx = blockIdx.x;
  int off, len; float scale = 1.0f;
  if (idx == 0)      { off = PART_VU; len = 2048; }
  else if (idx == 1) { off = PART_KU; len = 2048; }
  else if (idx == 2) { off = PART_VI; len = 2048; }
  else if (idx == 3) { off = PART_KI; len = 80;   }
  else               { off = PART_II; len = 4096; scale = 1.0f / 16777216.0f; }
  float s = 0.0f;
  for (int i = t; i < len; i += 256) s += part[off + i];
  red[t] = s; __syncthreads();
  for (int o = 128; o > 0; o >>= 1) {
    if (t < o) red[t] += red[t + o];
    __syncthreads();
  }
  if (t == 0) out[idx] = red[0] * scale;
}

// transpose: in (R x C) -> out (C x R). R=4096, C=2048.
__global__ void transpose_k(const float* __restrict__ in, float* __restrict__ out,
                            int R, int C) {
  __shared__ float tile[32][33];
  int bx = blockIdx.x * 32;
  int by = blockIdx.y * 32;
  int tx = threadIdx.x, ty = threadIdx.y;
#pragma unroll
  for (int q = 0; q < 32; q += 8)
    tile[ty + q][tx] = in[(size_t)(by + ty + q) * C + (bx + tx)];
  __syncthreads();
#pragma unroll
  for (int q = 0; q < 32; q += 8)
    out[(size_t)(bx + ty + q) * R + (by + tx)] = tile[tx][ty + q];
}

// ---------------------------------------------------------------------------
// X = A (M x 64) @ B (N x 64)^T, 64x64 tile per block (fp32; feeds hinges).
// ---------------------------------------------------------------------------
__global__ __launch_bounds__(256) void gemm_nt(
    const float* __restrict__ Arows, const float* __restrict__ Brows,
    float* __restrict__ X, int N) {
  __shared__ __align__(16) float At[64 * 68];
  __shared__ __align__(16) float Bt[64 * 68];
  const int t = threadIdx.x;
  const int i0 = blockIdx.x * 64, j0 = blockIdx.y * 64;
  for (int idx = t; idx < 1024; idx += 256) {
    int row = idx >> 4, q = idx & 15;
    float4 va = *(const float4*)(Arows + (size_t)(i0 + row) * 64 + 4 * q);
    At[(4 * q + 0) * 68 + row] = va.x; At[(4 * q + 1) * 68 + row] = va.y;
    At[(4 * q + 2) * 68 + row] = va.z; At[(4 * q + 3) * 68 + row] = va.w;
    float4 vb = *(const float4*)(Brows + (size_t)(j0 + row) * 64 + 4 * q);
    Bt[(4 * q + 0) * 68 + row] = vb.x; Bt[(4 * q + 1) * 68 + row] = vb.y;
    Bt[(4 * q + 2) * 68 + row] = vb.z; Bt[(4 * q + 3) * 68 + row] = vb.w;
  }
  __syncthreads();
  const int ti = t >> 4, tj = t & 15;
  float acc[4][4] = {{0.f,0.f,0.f,0.f},{0.f,0.f,0.f,0.f},{0.f,0.f,0.f,0.f},{0.f,0.f,0.f,0.f}};
  for (int k = 0; k < 64; ++k) {
    const float4 a = *(const float4*)&At[k * 68 + 4 * ti];
    const float4 b = *(const float4*)&Bt[k * 68 + 4 * tj];
    const float av[4] = {a.x, a.y, a.z, a.w};
    const float bv[4] = {b.x, b.y, b.z, b.w};
#pragma unroll
    for (int p = 0; p < 4; ++p)
#pragma unroll
      for (int q2 = 0; q2 < 4; ++q2) acc[p][q2] += av[p] * bv[q2];
  }
#pragma unroll
  for (int p = 0; p < 4; ++p) {
    float4 w = make_float4(acc[p][0], acc[p][1], acc[p][2], acc[p][3]);
    *(float4*)(X + (size_t)(i0 + 4 * ti + p) * N + j0 + 4 * tj) = w;
  }
}

// ---------------------------------------------------------------------------
// ii via bf16 MFMA, atomic-free: per-block partial |D-S| sum -> part slot.
// D round-trips LDS (aliased onto dead A/B staging; stride 68 = 2-way free)
// so structure is read as coalesced float4.
// ---------------------------------------------------------------------------
__global__ __launch_bounds__(256) void ii_mfma(
    const float* __restrict__ Kitem, const float* __restrict__ Vitem,
    const float* __restrict__ structure_, float* __restrict__ out,
    float* __restrict__ part) {
  __shared__ __align__(16) uint32_t smem[4352];   // Ab[2080] Bb[2080] / Dsh[4352]
  __shared__ float red[256];
  uint32_t* Ab = smem;
  uint32_t* Bb = smem + 2080;
  float* Dsh = (float*)smem;
  const int t = threadIdx.x;
  const int i0 = blockIdx.x * 64, j0 = blockIdx.y * 64;

  // stage: thread t handles row m = t>>2, 16-col chunk cq = t&3
  {
    const int m = t >> 2, cq = t & 3;
    const int kk = cq >> 1;
    const int q0 = (cq & 1) * 2;
    const int R = (m >> 4) * 2 + kk;
    const int m15 = m & 15;
    const float4* sa = (const float4*)(Kitem + (size_t)(i0 + m) * 64 + cq * 16);
    const float4* sb = (const float4*)(Vitem + (size_t)(j0 + m) * 64 + cq * 16);
    float4 a0 = sa[0], a1 = sa[1], a2 = sa[2], a3 = sa[3];
    float4 b0 = sb[0], b1 = sb[1], b2 = sb[2], b3 = sb[3];
    uint4 ca0 = make_uint4(bfpack(a0.x, a0.y), bfpack(a0.z, a0.w),
                           bfpack(a1.x, a1.y), bfpack(a1.z, a1.w));
    uint4 ca1 = make_uint4(bfpack(a2.x, a2.y), bfpack(a2.z, a2.w),
                           bfpack(a3.x, a3.y), bfpack(a3.z, a3.w));
    uint4 cb0 = make_uint4(bfpack(b0.x, b0.y), bfpack(b0.z, b0.w),
                           bfpack(b1.x, b1.y), bfpack(b1.z, b1.w));
    uint4 cb1 = make_uint4(bfpack(b2.x, b2.y), bfpack(b2.z, b2.w),
                           bfpack(b3.x, b3.y), bfpack(b3.z, b3.w));
    const int o0 = R * 260 + (((q0 + 0) << 4) | m15) * 4;
    const int o1 = R * 260 + (((q0 + 1) << 4) | m15) * 4;
    *(uint4*)(Ab + o0) = ca0;  *(uint4*)(Ab + o1) = ca1;
    *(uint4*)(Bb + o0) = cb0;  *(uint4*)(Bb + o1) = cb1;
  }
  __syncthreads();

  const int w = t >> 6, l = t & 63;
  short8 afr0 = *(const short8*)(Ab + (w * 2 + 0) * 260 + l * 4);
  short8 afr1 = *(const short8*)(Ab + (w * 2 + 1) * 260 + l * 4);
  f32x4 acc[4];
#pragma unroll
  for (int ct = 0; ct < 4; ++ct) {
    short8 bfr0 = *(const short8*)(Bb + (ct * 2 + 0) * 260 + l * 4);
    short8 bfr1 = *(const short8*)(Bb + (ct * 2 + 1) * 260 + l * 4);
    f32x4 a = {0.0f, 0.0f, 0.0f, 0.0f};
    a = __builtin_amdgcn_mfma_f32_16x16x32_bf16(afr0, bfr0, a, 0, 0, 0);
    a = __builtin_amdgcn_mfma_f32_16x16x32_bf16(afr1, bfr1, a, 0, 0, 0);
    acc[ct] = a;
  }
  __syncthreads();   // Ab/Bb dead; reuse as Dsh

  // scatter D (C/D: col=l&15, row=(l>>4)*4+reg) into row-major Dsh
  const int col = l & 15, rquad = l >> 4;
#pragma unroll
  for (int ct = 0; ct < 4; ++ct)
#pragma unroll
    for (int reg = 0; reg < 4; ++reg)
      Dsh[(w * 16 + rquad * 4 + reg) * 68 + ct * 16 + col] = acc[ct][reg];
  __syncthreads();

  // coalesced epilogue: thread t -> row t>>2, 16-col chunk (t&3)*16
  const int row = t >> 2, c0q = (t & 3) * 16;
  const float4* srow = (const float4*)(structure_ + (size_t)(i0 + row) * 4096 + j0 + c0q);
  const float4* drow = (const float4*)(Dsh + row * 68 + c0q);
  float s = 0.0f;
#pragma unroll
  for (int q = 0; q < 4; ++q) {
    float4 sv = srow[q];
    float4 dv = drow[q];
    s += fabsf(dv.x - sv.x) + fabsf(dv.y - sv.y)
       + fabsf(dv.z - sv.z) + fabsf(dv.w - sv.w);
  }
  red[t] = s; __syncthreads();
  for (int off = 128; off > 0; off >>= 1) {
    if (t < off) red[t] += red[t + off];
    __syncthreads();
  }
  if (t == 0) {
    if (part) part[blockIdx.y * gridDim.x + blockIdx.x] = red[0];
    else atomicAdd(out + 4, red[0] * (1.0f / 16777216.0f));
  }
}

// ---------------------------------------------------------------------------
// Contrast kernel v2 (Vu / Vi) — draw arithmetic FROZEN (absmax-64, r4-r6);
// result now stored to part[r] (no d_out atomic).
// ---------------------------------------------------------------------------
template <int C, int MODE, bool PRE>
__global__ __launch_bounds__(256) void contrast2(
    const float* __restrict__ padj_mat, size_t rs, size_t cs,
    const float* __restrict__ xmat,
    const float* __restrict__ A, const float* __restrict__ B,
    float* __restrict__ out, int out_idx, uint32_t salt,
    float* __restrict__ part) {
  constexpr int E = C / 256;
  constexpr int LOG2E = (E == 16) ? 4 : 3;
  constexpr int S = (E == 16) ? 260 : 264;
  constexpr int TSZ = (E - 1) * S + 256;
  constexpr int DEPTH = (C == 4096) ? 13 : 12;
  constexpr int NB = 512;
  __shared__ float T[TSZ];
  __shared__ int bs[NB + 1];
  __shared__ float x[PRE ? 1 : C];
  __shared__ __align__(16) float qa[PRE ? 4 : 64];
  __shared__ float red[256];
  __shared__ float wsumsh[4];
  __shared__ int s_pcnt, s_ncnt;
  const int t = threadIdx.x;
  const int r = blockIdx.x;
  const int lane = t & 63, wid = t >> 6;
  const float* xrow = PRE ? (xmat + (size_t)r * C) : nullptr;
  if (t == 0) { s_pcnt = 0; s_ncnt = 0; }
  if (!PRE && t < 64) qa[t] = A[(size_t)r * 64 + t];

  int lp = 0, ln = 0;
  for (int c = t; c < C; c += 256) {
    float v = padj_mat[(size_t)r * rs + (size_t)c * cs];
    T[(c & (E - 1)) * S + (c >> LOG2E)] = v;
    lp += (v > 0.0f) ? 1 : 0;
    if (MODE == 0) ln += (v <= 0.0f && c != r) ? 1 : 0;
    else           ln += ((1.0f - v) > 0.0f) ? 1 : 0;
  }
  if (lp) atomicAdd(&s_pcnt, lp);
  if (ln) atomicAdd(&s_ncnt, ln);
  __syncthreads();

  if (!PRE) {
    const int g = t >> 2, q = t & 3;
    const float4* qa4 = (const float4*)qa;
    for (int c = g; c < C; c += 64) {
      const float4* b4 = (const float4*)(B + (size_t)c * 64);
      float acc = 0.0f;
#pragma unroll
      for (int m = 0; m < 4; ++m) {
        float4 f = b4[q + 4 * m];
        float4 a = qa4[q + 4 * m];
        acc += f.x * a.x + f.y * a.y + f.z * a.z + f.w * a.w;
      }
      acc += __shfl_xor(acc, 1);
      acc += __shfl_xor(acc, 2);
      if (q == 0) x[c] = acc;
    }
    __syncthreads();
  }

  const int pcnt = s_pcnt, ncnt = s_ncnt;
  const int num = min(pcnt, ncnt);
  if (num == 0) return;
  const bool brA = (pcnt <= ncnt);

  auto wf = [&](float v, int c) -> float {
    if (brA) {
      if (MODE == 0) return (v <= 0.0f && c != r) ? 1.0f : 0.0f;
      float nv = 1.0f - v; return nv > 0.0f ? nv : 0.0f;
    }
    return v > 0.0f ? v : 0.0f;
  };

  float csum = 0.0f;
#pragma unroll
  for (int e = 0; e < E; ++e) csum += wf(T[e * S + t], t * E + e);
  float ps = csum;
#pragma unroll
  for (int off = 1; off < 64; off <<= 1) {
    float o = __shfl_up(ps, off);
    if (lane >= off) ps += o;
  }
  if (lane == 63) wsumsh[wid] = ps;
  __syncthreads();
  float wbase = 0.0f;
  for (int w = 0; w < wid; ++w) wbase += wsumsh[w];
  float run = wbase + ps - csum;
  {
#pragma unroll
    for (int e = 0; e < E; ++e) {
      float w = wf(T[e * S + t], t * E + e);
      run += w;
      T[e * S + t] = run;
    }
  }
  __syncthreads();
  const float total = T[(E - 1) * S + 255];

  for (int i = t; i < NB; i += 256) {
    float ub = ((float)i / (float)NB) * total;
    int lo = 0, hi = C;
    for (int it = 0; it < DEPTH; ++it) {
      if (lo < hi) {
        int mid = (lo + hi) >> 1;
        float cv = T[(mid & (E - 1)) * S + (mid >> LOG2E)];
        if (cv <= ub) lo = mid + 1; else hi = mid;
      }
    }
    bs[i] = lo;
  }
  if (t == 0) bs[NB] = C;
  __syncthreads();

  float acc = 0.0f;
  for (int k = 0; k < E; k += 8) {
    int cj[8]; bool dj[8]; float uj[8]; int lo[8], hi[8]; float xc[8];
#pragma unroll
    for (int j = 0; j < 8; ++j) {
      int c = t + (k + j) * 256;
      cj[j] = c;
      float v = padj_mat[(size_t)r * rs + (size_t)c * cs];
      bool det = brA ? (v > 0.0f)
                     : (MODE == 0 ? (v <= 0.0f && c != r) : ((1.0f - v) > 0.0f));
      dj[j] = det;
      xc[j] = PRE ? xrow[c] : x[c];
      float f = mur_u01((uint32_t)(r * C + c), salt);
      uj[j] = f * total;
      int b = (int)(f * (float)NB);
      b = b < NB - 1 ? b : NB - 1; b = b > 0 ? b : 0;
      lo[j] = bs[b]; hi[j] = bs[b + 1];
    }
    for (int it = 0; it < 7; ++it) {
#pragma unroll
      for (int j = 0; j < 8; ++j) {
        int mid = (lo[j] + hi[j]) >> 1;
        float cv = T[(mid & (E - 1)) * S + (mid >> LOG2E)];
        if (lo[j] < hi[j]) {
          if (cv <= uj[j]) lo[j] = mid + 1; else hi[j] = mid;
        }
      }
    }
#pragma unroll
    for (int j = 0; j < 8; ++j) {
      if (dj[j]) {
        int s = lo[j] < C ? lo[j] : C - 1;
        float xs = PRE ? xrow[s] : x[s];
        float term = brA ? (xs - xc[j] + 1.0f) : (xc[j] - xs + 1.0f);
        acc += fmaxf(term, 0.0f);
      }
    }
  }
  red[t] = acc; __syncthreads();
  for (int off = 128; off > 0; off >>= 1) {
    if (t < off) red[t] += red[t + off];
    __syncthreads();
  }
  if (t == 0) {
    if (part) part[r] = red[0] / (float)num;
    else atomicAdd(out + out_idx, red[0] / (float)num);
  }
}

// ---------------------------------------------------------------------------
// Ku: EXACT reproduction — row arithmetic FROZEN (passed 6x); part store.
// ---------------------------------------------------------------------------
__global__ __launch_bounds__(256) void ku_kernel(
    const float* __restrict__ KUU, const float* __restrict__ Kuser,
    float* __restrict__ out,
    uint32_t kp0, uint32_t kp1, uint32_t kn0, uint32_t kn1,
    float* __restrict__ part) {
  const int C = 2048;
  constexpr int E = 8, LOG2E = 3, S = 264;
  constexpr int TSZ = (E - 1) * S + 256;
  __shared__ float T[TSZ];
  __shared__ float red[256];
  __shared__ int s_pcnt;
  const int t = threadIdx.x, r = blockIdx.x;
  const float* row = KUU + (size_t)r * 2051;
  if (t == 0) s_pcnt = 0;
  __syncthreads();
  int lp = 0;
  for (int c = t; c < C; c += 256) {
    float v = row[c];
    T[(c & (E - 1)) * S + (c >> LOG2E)] = v > 0.0f ? v : 0.0f;
    lp += (v > 0.0f) ? 1 : 0;
  }
  if (lp) atomicAdd(&s_pcnt, lp);
  __syncthreads();
  const int pcnt = s_pcnt;
  const float n0 = row[2048], n1 = row[2049], n2 = row[2050];
  const int ng0 = (n0 <= 0.0f), ng1 = (n1 <= 0.0f), ng2 = (n2 <= 0.0f);
  const int ncnt = ng0 + ng1 + ng2;
  const int num = min(pcnt, ncnt);
  if (num == 0) return;

  float csum = 0.0f;
#pragma unroll
  for (int e = 0; e < E; ++e) csum += T[e * S + t];
  red[t] = csum; __syncthreads();
  if (t == 0) {
    float run = 0.0f;
    for (int i = 0; i < 256; ++i) { float v = red[i]; red[i] = run; run += v; }
  }
  __syncthreads();
  {
    float run = red[t];
#pragma unroll
    for (int e = 0; e < E; ++e) { run += T[e * S + t]; T[e * S + t] = run; }
  }
  __syncthreads();
  const float total = T[(E - 1) * S + 255];

  if (pcnt > ncnt) {
    float term = 0.0f;
    if (t < num) {
      int ng[3] = {ng0, ng1, ng2};
      int det = -1, cnt = 0;
      for (int q = 0; q < 3; ++q) {
        if (ng[q]) { if (cnt == t) { det = q; break; } cnt++; }
      }
      float f = tf_u01(kp0, kp1, 0u, (uint32_t)(r * 3 + t));
      float u = f * total;
      int lo = 0, hi = C;
      while (lo < hi) {
        int mid = (lo + hi) >> 1;
        float cv = T[(mid & (E - 1)) * S + (mid >> LOG2E)];
        if (cv <= u) lo = mid + 1; else hi = mid;
      }
      int s = lo < C ? lo : C - 1;
      const float* qr = Kuser + (size_t)r * 64;
      const float* qs = Kuser + (size_t)s * 64;
      const float* qn = Kuser + (size_t)(2048 + det) * 64;
      float px = 0.0f, nx = 0.0f;
      for (int k = 0; k < 64; ++k) { float av = qr[k]; px += av * qs[k]; nx += av * qn[k]; }
      term = fmaxf(nx - px + 1.0f, 0.0f);
    }
    red[t] = term; __syncthreads();
    for (int off = 128; off > 0; off >>= 1) {
      if (t < off) red[t] += red[t + off];
      __syncthreads();
    }
    if (t == 0) {
      if (part) part[r] = red[0] / (float)num;
      else atomicAdd(out + 1, red[0] / (float)num);
    }
  } else {
    if (t == 0) {
      float pv[3]; int pi[3]; int np = 0;
      for (int c = 0; c < C; ++c) {
        float v = row[c];
        if (v > 0.0f) { if (np < 3) { pv[np] = v; pi[np] = c; } np++; }
      }
      for (int a2 = 1; a2 < np; ++a2) {
        float v = pv[a2]; int id = pi[a2]; int b2 = a2 - 1;
        while (b2 >= 0 && pv[b2] > v) { pv[b2 + 1] = pv[b2]; pi[b2 + 1] = pi[b2]; b2--; }
        pv[b2 + 1] = v; pi[b2 + 1] = id;
      }
      int ng[3] = {ng0, ng1, ng2};
      float ncdf[3]; float runn = 0.0f;
      for (int q = 0; q < 3; ++q) { runn += ng[q] ? 1.0f : 0.0f; ncdf[q] = runn; }
      float ss = 0.0f;
      for (int j = 0; j < num; ++j) {
        float f = tf_u01(kn0, kn1, 0u, (uint32_t)(r * 3 + j));
        float u = f * runn;
        int s = 0; while (s < 3 && ncdf[s] <= u) s++; if (s > 2) s = 2;
        int det = pi[np - num + j];
        const float* qr = Kuser + (size_t)r * 64;
        const float* qd = Kuser + (size_t)det * 64;
        const float* qn = Kuser + (size_t)(2048 + s) * 64;
        float px = 0.0f, nx = 0.0f;
        for (int k = 0; k < 64; ++k) { float av = qr[k]; px += av * qd[k]; nx += av * qn[k]; }
        ss += fmaxf(nx - px + 1.0f, 0.0f);
      }
      if (part) part[r] = ss / (float)num;
      else atomicAdd(out + 1, ss / (float)num);
    }
  }
}

// ---------------------------------------------------------------------------
// Ki pipeline — cdf/draw arithmetic FROZEN; ki_draw stores to part slots.
// ---------------------------------------------------------------------------
__global__ __launch_bounds__(256) void ki_prep(
    const float* __restrict__ preference,
    float* __restrict__ cdf_ws, float* __restrict__ vals_ws,
    int* __restrict__ rank_ws, float* __restrict__ meta) {
  const int C = 4096;
  __shared__ float cdf[4096];
  __shared__ float red[256];
  __shared__ int s_pcnt;
  const int t = threadIdx.x, r = blockIdx.x;
  if (t == 0) s_pcnt = 0;
  __syncthreads();
  for (int i = r * 256 + t; i < 5 * C; i += 5 * 256) rank_ws[i] = 0;
  int lp = 0;
  for (int c = t; c < C; c += 256) {
    float v = preference[(size_t)c * 5 + r];
    lp += (v > 0.0f) ? 1 : 0;
    cdf[c] = 1.0f - v;
    vals_ws[(size_t)r * C + c] = v;
  }
  if (lp) atomicAdd(&s_pcnt, lp);
  __syncthreads();
  const int num = s_pcnt;
  const int E = C >> 8;
  const int base = t * E;
  float csum = 0.0f;
  for (int e = 0; e < E; ++e) csum += cdf[base + e];
  red[t] = csum; __syncthreads();
  if (t == 0) {
    float run = 0.0f;
    for (int i = 0; i < 256; ++i) { float v = red[i]; red[i] = run; run += v; }
  }
  __syncthreads();
  {
    float run = red[t];
    for (int e = 0; e < E; ++e) { float w = cdf[base + e]; run += w; cdf[base + e] = run; }
  }
  __syncthreads();
  for (int c = t; c < C; c += 256) cdf_ws[(size_t)r * C + c] = cdf[c];
  if (t == 0) { meta[2 * r] = (float)num; meta[2 * r + 1] = cdf[C - 1]; }
}

__global__ __launch_bounds__(256) void ki_rank_p(
    const float* __restrict__ vals_ws, int* __restrict__ rank_ws) {
  const int C = 4096;
  __shared__ __align__(16) float sv[256];
  const int t = threadIdx.x;
  const int r = blockIdx.y;
  const int z = blockIdx.z;
  const int c0 = blockIdx.x * 256 + t;
  const float* vrow = vals_ws + (size_t)r * C;
  sv[t] = vrow[z * 256 + t];
  __syncthreads();
  const float v0 = vrow[c0];
  const int cbase = z * 256;
  int rank = 0;
  const float4* sv4 = (const float4*)sv;
#pragma unroll 8
  for (int q = 0; q < 64; ++q) {
    float4 w = sv4[q];
    int cb = cbase + 4 * q;
    rank += (w.x < v0 || (w.x == v0 && cb + 0 < c0)) ? 1 : 0;
    rank += (w.y < v0 || (w.y == v0 && cb + 1 < c0)) ? 1 : 0;
    rank += (w.z < v0 || (w.z == v0 && cb + 2 < c0)) ? 1 : 0;
    rank += (w.w < v0 || (w.w == v0 && cb + 3 < c0)) ? 1 : 0;
  }
  if (rank) atomicAdd(&rank_ws[(size_t)r * C + c0], rank);
}

__global__ __launch_bounds__(256) void ki_scatter(
    const int* __restrict__ rank_ws, int* __restrict__ sorted_ws) {
  const int C = 4096;
  const int t = threadIdx.x;
  const int r = blockIdx.y;
  const int c0 = blockIdx.x * 256 + t;
  sorted_ws[(size_t)r * C + rank_ws[(size_t)r * C + c0]] = c0;
}

__global__ __launch_bounds__(256) void ki_draw(
    const float* __restrict__ cdf_ws, const int* __restrict__ sorted_ws,
    const float* __restrict__ meta,
    const float* __restrict__ Kuser, const float* __restrict__ Kitem,
    float* __restrict__ out, uint32_t kn0, uint32_t kn1,
    float* __restrict__ part) {
  const int C = 4096;
  __shared__ float cdf[4096];
  __shared__ __align__(16) float qa[64];
  __shared__ float red[256];
  const int t = threadIdx.x;
  const int r = blockIdx.y;
  const int j = blockIdx.x * 256 + t;
  if (t < 64) qa[t] = Kuser[(size_t)r * 64 + t];
  for (int c = t; c < C; c += 256) cdf[c] = cdf_ws[(size_t)r * C + c];
  __syncthreads();
  const int num = (int)meta[2 * r];
  const float total = meta[2 * r + 1];
  float acc = 0.0f;
  if (j < num) {
    float f = tf_u01(kn0, kn1, 0u, (uint32_t)(r * 4096 + j));
    float u = f * total;
    int s = bsearch_right(cdf, C, u);
    int det = sorted_ws[(size_t)r * C + (C - num + j)];
    const float4* qa4 = (const float4*)qa;
    const float4* bsv = (const float4*)(Kitem + (size_t)s * 64);
    const float4* bdv = (const float4*)(Kitem + (size_t)det * 64);
    float xs = 0.0f, xd = 0.0f;
#pragma unroll
    for (int m = 0; m < 16; ++m) {
      float4 a4 = qa4[m]; float4 v1 = bsv[m]; float4 v2 = bdv[m];
      xs += a4.x * v1.x + a4.y * v1.y + a4.z * v1.z + a4.w * v1.w;
      xd += a4.x * v2.x + a4.y * v2.y + a4.z * v2.z + a4.w * v2.w;
    }
    acc = fmaxf(xs - xd + 1.0f, 0.0f) / (float)num;
  }
  red[t] = acc; __syncthreads();
  for (int off = 128; off > 0; off >>= 1) {
    if (t < off) red[t] += red[t + off];
    __syncthreads();
  }
  if (t == 0) {
    if (part) part[r * 16 + blockIdx.x] = red[0];
    else if (red[0] != 0.0f) atomicAdd(out + 3, red[0]);
  }
}

// Monolithic Ki fallback (tiny-ws path; atomics retained).
__global__ __launch_bounds__(256) void ki_kernel(
    const float* __restrict__ preference, const float* __restrict__ Kuser,
    const float* __restrict__ Kitem, float* __restrict__ out,
    uint32_t kn0, uint32_t kn1) {
  const int C = 4096;
  __shared__ float cdf[4096];
  __shared__ unsigned long long skey[4096];
  __shared__ __align__(16) float qa[64];
  __shared__ float red[256];
  __shared__ int s_pcnt;
  const int t = threadIdx.x, r = blockIdx.x;
  if (t == 0) s_pcnt = 0;
  if (t < 64) qa[t] = Kuser[(size_t)r * 64 + t];
  __syncthreads();
  int lp = 0;
  for (int c = t; c < C; c += 256) {
    float v = preference[(size_t)c * 5 + r];
    lp += (v > 0.0f) ? 1 : 0;
    cdf[c] = 1.0f - v;
    skey[c] = ((unsigned long long)__float_as_uint(v) << 32) | (unsigned)c;
  }
  if (lp) atomicAdd(&s_pcnt, lp);
  __syncthreads();
  const int num = s_pcnt;
  if (num == 0) return;
  const int E = C >> 8;
  const int base = t * E;
  float csum = 0.0f;
  for (int e = 0; e < E; ++e) csum += cdf[base + e];
  red[t] = csum; __syncthreads();
  if (t == 0) {
    float run = 0.0f;
    for (int i = 0; i < 256; ++i) { float v = red[i]; red[i] = run; run += v; }
  }
  __syncthreads();
  {
    float run = red[t];
    for (int e = 0; e < E; ++e) { float w = cdf[base + e]; run += w; cdf[base + e] = run; }
  }
  __syncthreads();
  const float total = cdf[C - 1];
  for (int k = 2; k <= C; k <<= 1) {
    for (int j2 = k >> 1; j2 > 0; j2 >>= 1) {
      for (int i = t; i < C; i += 256) {
        int ixj = i ^ j2;
        if (ixj > i) {
          unsigned long long a = skey[i], b = skey[ixj];
          bool up = ((i & k) == 0);
          if ((a > b) == up) { skey[i] = b; skey[ixj] = a; }
        }
      }
      __syncthreads();
    }
  }
  float acc = 0.0f;
  const float4* qa4 = (const float4*)qa;
  for (int j = t; j < num; j += 256) {
    float f = tf_u01(kn0, kn1, 0u, (uint32_t)(r * 4096 + j));
    float u = f * total;
    int s = bsearch_right(cdf, C, u);
    int det = (int)(skey[C - num + j] & 0xffffffffull);
    const float4* bsv = (const float4*)(Kitem + (size_t)s * 64);
    const float4* bdv = (const float4*)(Kitem + (size_t)det * 64);
    float xs = 0.0f, xd = 0.0f;
#pragma unroll
    for (int m = 0; m < 16; ++m) {
      float4 a4 = qa4[m]; float4 v1 = bsv[m]; float4 v2 = bdv[m];
      xs += a4.x * v1.x + a4.y * v1.y + a4.z * v1.z + a4.w * v1.w;
      xd += a4.x * v2.x + a4.y * v2.y + a4.z * v2.z + a4.w * v2.w;
    }
    acc += fmaxf(xs - xd + 1.0f, 0.0f);
  }
  red[t] = acc; __syncthreads();
  for (int off = 128; off > 0; off >>= 1) {
    if (t < off) red[t] += red[t + off];
    __syncthreads();
  }
  if (t == 0) atomicAdd(out + 3, red[0] / (float)num);
}

// ---------------------------------------------------------------------------
extern "C" void kernel_launch(void* const* d_in, const int* in_sizes, int n_in,
                              void* d_out, int out_size, void* d_ws, size_t ws_size,
                              hipStream_t stream) {
  const float* KUU   = (const float*)d_in[0];  // 2051 x 2051
  const float* VUU   = (const float*)d_in[1];  // 2048 x 2048
  const float* Vuser = (const float*)d_in[2];  // 2048 x 64
  const float* Vitem = (const float*)d_in[3];  // 4096 x 64
  const float* Kuser = (const float*)d_in[4];  // 2051 x 64
  const float* Kitem = (const float*)d_in[5];  // 4096 x 64
  const float* pref  = (const float*)d_in[7];  // 4096 x 5
  const float* Vpref = (const float*)d_in[8];  // 4096 x 2048
  const float* structure_ = (const float*)d_in[9];  // 4096 x 4096
  float* out = (float*)d_out;  // 5 floats: (Vu, Ku, Vi, Ki, ii)

  uint32_t k1a, k1b, k3a, k3b;
  tf2x32(0u, 42u, 0u, 1u, &k1a, &k1b);  // k1 (Ku call)
  tf2x32(0u, 42u, 0u, 3u, &k3a, &k3b);  // k3 (Ki call)
  uint32_t kup0, kup1, kun0, kun1, kin0, kin1;
  tf2x32(k1a, k1b, 0u, 0u, &kup0, &kup1);
  tf2x32(k1a, k1b, 0u, 1u, &kun0, &kun1);
  tf2x32(k3a, k3b, 0u, 1u, &kin0, &kin1);

  const uint32_t SALT_VU = 0x8AF1B0C2u;
  const uint32_t SALT_VI = 0x5F356495u;

  // ws layout (full): [VUIt 32M][Xvi 32M][Xvu 16M][ki ~336K][part ~41K]
  const size_t vuit_bytes = (size_t)2048 * 4096 * sizeof(float);
  const size_t xvi_bytes  = (size_t)2048 * 4096 * sizeof(float);
  const size_t xvu_bytes  = (size_t)2048 * 2048 * sizeof(float);
  const size_t ki_bytes   = (size_t)(4 * 5 * 4096 + 16) * sizeof(float);
  const size_t part_bytes = (size_t)PART_LEN * sizeof(float);
  const size_t full_bytes = vuit_bytes + xvi_bytes + xvu_bytes + ki_bytes + part_bytes;

  const bool full = ws_size >= full_bytes;
  const bool mid  = !full && ws_size >= vuit_bytes + ki_bytes + part_bytes;

  if (full || mid) {
    float* VUIt = (float*)d_ws;
    float* Xvi  = full ? (float*)((char*)d_ws + vuit_bytes) : nullptr;
    float* Xvu  = full ? (float*)((char*)d_ws + vuit_bytes + xvi_bytes) : nullptr;
    char*  kib  = (char*)d_ws + (full ? vuit_bytes + xvi_bytes + xvu_bytes : vuit_bytes);
    float* cdf_ws  = (float*)kib;
    float* vals_ws = cdf_ws + 5 * 4096;
    int*   sorted_ws = (int*)(vals_ws + 5 * 4096);
    int*   rank_ws = sorted_ws + 5 * 4096;
    float* meta = (float*)(rank_ws + 5 * 4096);
    float* part = meta + 16;

    hipLaunchKernelGGL(zero_part, dim3(16), dim3(256), 0, stream, part);

    hipLaunchKernelGGL(ki_prep, dim3(5), dim3(256), 0, stream,
                       pref, cdf_ws, vals_ws, rank_ws, meta);
    hipLaunchKernelGGL(ki_rank_p, dim3(16, 5, 16), dim3(256), 0, stream,
                       vals_ws, rank_ws);
    hipLaunchKernelGGL(ki_scatter, dim3(16, 5), dim3(256), 0, stream,
                       rank_ws, sorted_ws);
    hipLaunchKernelGGL(ki_draw, dim3(16, 5), dim3(256), 0, stream,
                       cdf_ws, sorted_ws, meta, Kuser, Kitem, out, kin0, kin1,
                       part + PART_KI);

    hipLaunchKernelGGL(transpose_k, dim3(64, 128), dim3(32, 8), 0, stream,
                       Vpref, VUIt, 4096, 2048);
    if (full) {
      hipLaunchKernelGGL(gemm_nt, dim3(32, 32), dim3(256), 0, stream,
                         Vuser, Vuser, Xvu, 2048);
      hipLaunchKernelGGL(gemm_nt, dim3(32, 64), dim3(256), 0, stream,
                         Vuser, Vitem, Xvi, 4096);
    }
    hipLaunchKernelGGL(ii_mfma, dim3(64, 64), dim3(256), 0, stream,
                       Kitem, Vitem, structure_, out, part + PART_II);

    if (full) {
      hipLaunchKernelGGL((contrast2<2048, 0, true>), dim3(2048), dim3(256), 0, stream,
                         VUU, (size_t)2048, (size_t)1, Xvu, nullptr, nullptr,
                         out, 0, SALT_VU, part + PART_VU);
    } else {
      hipLaunchKernelGGL((contrast2<2048, 0, false>), dim3(2048), dim3(256), 0, stream,
                         VUU, (size_t)2048, (size_t)1, nullptr, Vuser, Vuser,
                         out, 0, SALT_VU, part + PART_VU);
    }
    hipLaunchKernelGGL(ku_kernel, dim3(2048), dim3(256), 0, stream,
                       KUU, Kuser, out, kup0, kup1, kun0, kun1, part + PART_KU);
    if (full) {
      hipLaunchKernelGGL((contrast2<4096, 1, true>), dim3(2048), dim3(256), 0, stream,
                         VUIt, (size_t)4096, (size_t)1, Xvi, nullptr, nullptr,
                         out, 2, SALT_VI, part + PART_VI);
    } else {
      hipLaunchKernelGGL((contrast2<4096, 1, false>), dim3(2048), dim3(256), 0, stream,
                         VUIt, (size_t)4096, (size_t)1, nullptr, Vuser, Vitem,
                         out, 2, SALT_VI, part + PART_VI);
    }

    hipLaunchKernelGGL(final_reduce, dim3(5), dim3(256), 0, stream, part, out);
  } else {
    // tiny-ws fallback: original atomic behavior
    hipLaunchKernelGGL(init_out, dim3(1), dim3(64), 0, stream, out);
    hipLaunchKernelGGL(ii_mfma, dim3(64, 64), dim3(256), 0, stream,
                       Kitem, Vitem, structure_, out, (float*)nullptr);
    hipLaunchKernelGGL((contrast2<2048, 0, false>), dim3(2048), dim3(256), 0, stream,
                       VUU, (size_t)2048, (size_t)1, nullptr, Vuser, Vuser,
                       out, 0, SALT_VU, (float*)nullptr);
    hipLaunchKernelGGL(ku_kernel, dim3(2048), dim3(256), 0, stream,
                       KUU, Kuser, out, kup0, kup1, kun0, kun1, (float*)nullptr);
    hipLaunchKernelGGL((contrast2<4096, 1, false>), dim3(2048), dim3(256), 0, stream,
                       Vpref, (size_t)1, (size_t)2048, nullptr, Vuser, Vitem,
                       out, 2, SALT_VI, (float*)nullptr);
    hipLaunchKernelGGL(ki_kernel, dim3(5), dim3(256), 0, stream,
                       pref, Kuser, Kitem, out, kin0, kin1);
  }
}